// Round 7
// baseline (410.147 us; speedup 1.0000x reference)
//
#include <hip/hip_runtime.h>
#include <math.h>

typedef unsigned short u16;
typedef __bf16 bf16x8 __attribute__((ext_vector_type(8)));
typedef short s16x4 __attribute__((ext_vector_type(4)));
typedef short s16x8 __attribute__((ext_vector_type(8)));
typedef float f32x4 __attribute__((ext_vector_type(4)));

#define B_ 2
#define S_ 2048
#define D_ 2048
#define H_ 16
#define HD_ 128
#define M_ 4096
#define N3_ 6144

#define AS1(p) ((__attribute__((address_space(1))) void*)(void*)(p))
#define AS3(p) ((__attribute__((address_space(3))) void*)(p))
#define GLD16(g, l) __builtin_amdgcn_global_load_lds(AS1(g), AS3(l), 16, 0, 0)

__device__ __forceinline__ u16 f2bf(float f) {
  unsigned u = __float_as_uint(f);
  return (u16)((u + 0x7FFFu + ((u >> 16) & 1u)) >> 16);
}
__device__ __forceinline__ float bf2f(u16 v) {
  return __uint_as_float(((unsigned)v) << 16);
}

// ---------------- fp32 -> bf16 convert, all 5 tensors in one launch ----------------
__global__ void cvt5_k(const float* __restrict__ x, const float* __restrict__ wq,
                       const float* __restrict__ wk, const float* __restrict__ wv,
                       const float* __restrict__ wo, u16* __restrict__ xb,
                       u16* __restrict__ wqkvb, u16* __restrict__ wob) {
  int y = blockIdx.y;
  const float* s;
  u16* d;
  int n4;
  if (y == 0) {
    s = x; d = xb; n4 = M_ * D_ / 4;
  } else {
    s = (y == 1) ? wq : (y == 2) ? wk : (y == 3) ? wv : wo;
    d = (y == 4) ? wob : wqkvb + (size_t)(y - 1) * D_ * D_;
    n4 = D_ * D_ / 4;
  }
  int i = blockIdx.x * 256 + threadIdx.x;
  if (i >= n4) return;
  float4 v = ((const float4*)s)[i];
  ushort4 o;
  o.x = f2bf(v.x); o.y = f2bf(v.y); o.z = f2bf(v.z); o.w = f2bf(v.w);
  ((ushort4*)d)[i] = o;
}

// ---------------- RoPE cos/sin table (fp64 for accuracy) ----------------
__global__ void rope_tab_k(float2* __restrict__ tab) {
  int t = blockIdx.x * 256 + threadIdx.x;
  if (t >= S_ * 64) return;
  int s = t >> 6, i = t & 63;
  double inv = exp2(-(double)i * (13.287712379549449 / 64.0)); // 10000^(-i/64)
  double fr = (double)s * inv;
  double sv, cv;
  sincos(fr, &sv, &cv);
  tab[t] = make_float2((float)cv, (float)sv);
}

// ---------------- 256x256 8-phase GEMM (round-3 proven: 125.6us, 0 conflicts) ----
template <typename OT>
__global__ __launch_bounds__(512, 2) void gemm256_k(const u16* __restrict__ A,
                                                    const u16* __restrict__ B,
                                                    OT* __restrict__ C,
                                                    int M, int N, int K) {
  __shared__ alignas(16) u16 sm[65536]; // A0 A1 B0 B1, 16384 u16 each
  const int tid = threadIdx.x;
  const int wid = tid >> 6, lane = tid & 63;
  const int quad = lane >> 4, l16 = lane & 15;
  const int wr = wid >> 2, wc = wid & 3;

  const int nby = M >> 8, nbx = N >> 8, nwg = nbx * nby;
  int bid = blockIdx.x;
  int wg = (nwg % 8 == 0) ? (bid % 8) * (nwg >> 3) + (bid >> 3) : bid;
  const int m0 = (wg % nby) << 8, n0 = (wg / nby) << 8;

  const int rr = tid >> 3;
  const int sw8 = ((tid & 7) ^ (rr & 7)) * 8;
  const int gb0 = (rr & 31) + ((rr & 32) << 1);
  const u16* pA0_0 = A + (size_t)(m0 + rr) * K + sw8;
  const u16* pA0_1 = A + (size_t)(m0 + 128 + rr) * K + sw8;
  const u16* pA1_0 = A + (size_t)(m0 + 64 + rr) * K + sw8;
  const u16* pA1_1 = A + (size_t)(m0 + 192 + rr) * K + sw8;
  const u16* pB0_0 = B + (size_t)(n0 + gb0) * K + sw8;
  const u16* pB0_1 = B + (size_t)(n0 + 128 + gb0) * K + sw8;
  const u16* pB1_0 = B + (size_t)(n0 + 32 + gb0) * K + sw8;
  const u16* pB1_1 = B + (size_t)(n0 + 160 + gb0) * K + sw8;
  const int dst0 = wid * 64 * 8, dst1 = (512 + wid * 64) * 8;

  const int pj0 = (quad ^ (l16 & 7)) * 8;
  const int pj1 = ((4 + quad) ^ (l16 & 7)) * 8;

  f32x4 acc[8][4] = {};
  const int NT = K >> 6;

  GLD16(pA0_0, sm + dst0);
  GLD16(pA0_1, sm + dst1);
  GLD16(pB0_0, sm + 32768 + dst0);
  GLD16(pB0_1, sm + 32768 + dst1);
  GLD16(pB1_0, sm + 32768 + 8192 + dst0);
  GLD16(pB1_1, sm + 32768 + 8192 + dst1);
  GLD16(pA1_0, sm + 8192 + dst0);
  GLD16(pA1_1, sm + 8192 + dst1);
  asm volatile("s_waitcnt vmcnt(4)" ::: "memory");
  asm volatile("s_barrier" ::: "memory");

  int koff = 0;
#pragma unroll 1
  for (int t = 0; t < NT; ++t) {
    const int aB = (t & 1) * 16384, bB = 32768 + (t & 1) * 16384;
    const int aN = ((t + 1) & 1) * 16384, bN = 32768 + ((t + 1) & 1) * 16384;
    const bool pre = (t + 1 < NT);
    const int kn = koff + 64;
    bf16x8 a_[4][2], b_[4][2];

    // ---- P0
#pragma unroll
    for (int m = 0; m < 4; ++m) {
      int rb = aB + (wr * 64 + m * 16 + l16) * 64;
      a_[m][0] = *(const bf16x8*)&sm[rb + pj0];
      a_[m][1] = *(const bf16x8*)&sm[rb + pj1];
    }
#pragma unroll
    for (int n = 0; n < 2; ++n) {
      int rb = bB + (wc * 32 + n * 16 + l16) * 64;
      b_[n][0] = *(const bf16x8*)&sm[rb + pj0];
      b_[n][1] = *(const bf16x8*)&sm[rb + pj1];
    }
    if (pre) { GLD16(pA0_0 + kn, sm + aN + dst0); GLD16(pA0_1 + kn, sm + aN + dst1); }
    asm volatile("s_barrier" ::: "memory");
    __builtin_amdgcn_s_setprio(1);
#pragma unroll
    for (int m = 0; m < 4; ++m)
#pragma unroll
      for (int n = 0; n < 2; ++n) {
        acc[m][n] = __builtin_amdgcn_mfma_f32_16x16x32_bf16(a_[m][0], b_[n][0], acc[m][n], 0, 0, 0);
        acc[m][n] = __builtin_amdgcn_mfma_f32_16x16x32_bf16(a_[m][1], b_[n][1], acc[m][n], 0, 0, 0);
      }
    __builtin_amdgcn_s_setprio(0);
    if (pre) asm volatile("s_waitcnt vmcnt(4)" ::: "memory");
    else     asm volatile("s_waitcnt vmcnt(0)" ::: "memory");
    asm volatile("s_barrier" ::: "memory");

    // ---- P1
#pragma unroll
    for (int n = 0; n < 2; ++n) {
      int rb = bB + (128 + wc * 32 + n * 16 + l16) * 64;
      b_[2 + n][0] = *(const bf16x8*)&sm[rb + pj0];
      b_[2 + n][1] = *(const bf16x8*)&sm[rb + pj1];
    }
    if (pre) { GLD16(pB0_0 + kn, sm + bN + dst0); GLD16(pB0_1 + kn, sm + bN + dst1); }
    asm volatile("s_barrier" ::: "memory");
    __builtin_amdgcn_s_setprio(1);
#pragma unroll
    for (int m = 0; m < 4; ++m)
#pragma unroll
      for (int n = 0; n < 2; ++n) {
        acc[m][2 + n] = __builtin_amdgcn_mfma_f32_16x16x32_bf16(a_[m][0], b_[2 + n][0], acc[m][2 + n], 0, 0, 0);
        acc[m][2 + n] = __builtin_amdgcn_mfma_f32_16x16x32_bf16(a_[m][1], b_[2 + n][1], acc[m][2 + n], 0, 0, 0);
      }
    __builtin_amdgcn_s_setprio(0);
    if (pre) asm volatile("s_waitcnt vmcnt(4)" ::: "memory");
    else     asm volatile("s_waitcnt vmcnt(0)" ::: "memory");
    asm volatile("s_barrier" ::: "memory");

    // ---- P2
#pragma unroll
    for (int m = 0; m < 4; ++m) {
      int rb = aB + (128 + wr * 64 + m * 16 + l16) * 64;
      a_[m][0] = *(const bf16x8*)&sm[rb + pj0];
      a_[m][1] = *(const bf16x8*)&sm[rb + pj1];
    }
    if (pre) { GLD16(pB1_0 + kn, sm + bN + 8192 + dst0); GLD16(pB1_1 + kn, sm + bN + 8192 + dst1); }
    asm volatile("s_barrier" ::: "memory");
    __builtin_amdgcn_s_setprio(1);
#pragma unroll
    for (int m = 0; m < 4; ++m)
#pragma unroll
      for (int n = 0; n < 2; ++n) {
        acc[4 + m][n] = __builtin_amdgcn_mfma_f32_16x16x32_bf16(a_[m][0], b_[n][0], acc[4 + m][n], 0, 0, 0);
        acc[4 + m][n] = __builtin_amdgcn_mfma_f32_16x16x32_bf16(a_[m][1], b_[n][1], acc[4 + m][n], 0, 0, 0);
      }
    __builtin_amdgcn_s_setprio(0);
    asm volatile("s_barrier" ::: "memory");

    // ---- P3
    if (pre) { GLD16(pA1_0 + kn, sm + aN + 8192 + dst0); GLD16(pA1_1 + kn, sm + aN + 8192 + dst1); }
    asm volatile("s_barrier" ::: "memory");
    __builtin_amdgcn_s_setprio(1);
#pragma unroll
    for (int m = 0; m < 4; ++m)
#pragma unroll
      for (int n = 0; n < 2; ++n) {
        acc[4 + m][2 + n] = __builtin_amdgcn_mfma_f32_16x16x32_bf16(a_[m][0], b_[2 + n][0], acc[4 + m][2 + n], 0, 0, 0);
        acc[4 + m][2 + n] = __builtin_amdgcn_mfma_f32_16x16x32_bf16(a_[m][1], b_[2 + n][1], acc[4 + m][2 + n], 0, 0, 0);
      }
    __builtin_amdgcn_s_setprio(0);
    asm volatile("s_waitcnt vmcnt(4)" ::: "memory");
    asm volatile("s_barrier" ::: "memory");
    koff = kn;
  }

#pragma unroll
  for (int m = 0; m < 8; ++m) {
#pragma unroll
    for (int n = 0; n < 4; ++n) {
      int col = n0 + wc * 64 + n * 16 + l16;
#pragma unroll
      for (int r = 0; r < 4; ++r) {
        int row = m0 + wr * 128 + m * 16 + quad * 4 + r;
        if constexpr (sizeof(OT) == 4)
          C[(size_t)row * N + col] = acc[m][n][r];
        else
          C[(size_t)row * N + col] = f2bf(acc[m][n][r]);
      }
    }
  }
}

// ---------------- GEMM: 128^2 2-phase (out-proj) ----------------
template <typename OT>
__global__ __launch_bounds__(256) void gemm_bt_k(const u16* __restrict__ A,
                                                 const u16* __restrict__ B,
                                                 OT* __restrict__ C,
                                                 int M, int N, int K) {
  __shared__ alignas(16) u16 As[128 * 32];
  __shared__ alignas(16) u16 Bs[128 * 32];
  const int tid = threadIdx.x;
  const int wave = tid >> 6, lane = tid & 63;
  const int quad = lane >> 4, l16 = lane & 15;
  const int m0 = blockIdx.y * 128, n0 = blockIdx.x * 128;
  const int wm = (wave >> 1) * 64, wn = (wave & 1) * 64;
  const u16* Ag = A + (size_t)m0 * K;
  const u16* Bg = B + (size_t)n0 * K;
  f32x4 acc[4][4] = {};
  const int c0 = tid, c1 = tid + 256;
  const int r0 = c0 >> 2, k0b = (c0 & 3) * 8;
  const int r1 = c1 >> 2, k1b = (c1 & 3) * 8;
  u16* la0 = As + (size_t)(wave * 64) * 8;
  u16* la1 = As + (size_t)(256 + wave * 64) * 8;
  u16* lb0 = Bs + (size_t)(wave * 64) * 8;
  u16* lb1 = Bs + (size_t)(256 + wave * 64) * 8;
  for (int kt = 0; kt < K; kt += 32) {
    GLD16(Ag + (size_t)r0 * K + kt + k0b, la0);
    GLD16(Ag + (size_t)r1 * K + kt + k1b, la1);
    GLD16(Bg + (size_t)r0 * K + kt + k0b, lb0);
    GLD16(Bg + (size_t)r1 * K + kt + k1b, lb1);
    __syncthreads();
    bf16x8 af[4], bfr[4];
#pragma unroll
    for (int i = 0; i < 4; ++i)
      af[i] = *(const bf16x8*)&As[(wm + i * 16 + l16) * 32 + quad * 8];
#pragma unroll
    for (int j = 0; j < 4; ++j)
      bfr[j] = *(const bf16x8*)&Bs[(wn + j * 16 + l16) * 32 + quad * 8];
#pragma unroll
    for (int i = 0; i < 4; ++i)
#pragma unroll
      for (int j = 0; j < 4; ++j)
        acc[i][j] = __builtin_amdgcn_mfma_f32_16x16x32_bf16(af[i], bfr[j], acc[i][j], 0, 0, 0);
    __syncthreads();
  }
#pragma unroll
  for (int i = 0; i < 4; ++i) {
#pragma unroll
    for (int j = 0; j < 4; ++j) {
      int n = n0 + wn + j * 16 + l16;
#pragma unroll
      for (int r = 0; r < 4; ++r) {
        int m = m0 + wm + i * 16 + quad * 4 + r;
        if constexpr (sizeof(OT) == 4)
          C[(size_t)m * N + n] = acc[i][j][r];
        else
          C[(size_t)m * N + n] = f2bf(acc[i][j][r]);
      }
    }
  }
}

// ---------------- RoPE apply + relayout q,k -> [b*H+h][s][d] ----------------
// Q additionally pre-scaled by 1/sqrt(128)*log2(e) so flash applies exp2 directly.
__global__ void rope_k(const u16* __restrict__ qkv, const float2* __restrict__ tab,
                       u16* __restrict__ Qr, u16* __restrict__ Kr) {
  const float SCLQ = 0.08838834764831845f * 1.4426950408889634f;
  int t = blockIdx.x * 256 + threadIdx.x; // M_*H_*64
  int m = t >> 10;
  int h = (t >> 6) & 15;
  int i = t & 63;
  int s = m & (S_ - 1);
  int b = m >> 11;
  float2 cs = tab[(s << 6) | i];
  const u16* qp = qkv + (size_t)m * N3_ + h * HD_ + 2 * i;
  ushort2 qv = *(const ushort2*)qp;
  ushort2 kv = *(const ushort2*)(qp + D_);
  float qr = bf2f(qv.x), qi = bf2f(qv.y);
  float kr = bf2f(kv.x), ki = bf2f(kv.y);
  ushort2 qo, ko;
  qo.x = f2bf((qr * cs.x - qi * cs.y) * SCLQ);
  qo.y = f2bf((qr * cs.y + qi * cs.x) * SCLQ);
  ko.x = f2bf(kr * cs.x - ki * cs.y);
  ko.y = f2bf(kr * cs.y + ki * cs.x);
  size_t o = ((size_t)(b * H_ + h) * S_ + s) * HD_ + 2 * i;
  *(ushort2*)(Qr + o) = qo;
  *(ushort2*)(Kr + o) = ko;
}

// ---------------- V permute: qkv v-part -> Vp[bh][s/4][d][4] ----------------
__global__ __launch_bounds__(256) void vperm_k(const u16* __restrict__ qkv,
                                               u16* __restrict__ Vp) {
  int bh = blockIdx.y;
  int b = bh >> 4, h = bh & 15;
  int t = blockIdx.x * 256 + threadIdx.x; // 0 .. S_*HD_/4-1 ; t = g*128 + d
  int d = t & 127, g = t >> 7;
  const u16* src = qkv + ((size_t)(b * S_ + 4 * g)) * N3_ + 2 * D_ + h * HD_ + d;
  ushort4 o;
  o.x = src[0];
  o.y = src[N3_];
  o.z = src[2 * N3_];
  o.w = src[3 * N3_];
  *(ushort4*)(Vp + (size_t)bh * S_ * HD_ + (size_t)t * 4) = o;
}

// ---------------- Flash attention, q-tile 256, 16 waves, 4 waves/SIMD ----------------
// 1024 threads = 16 waves, each owning 16 q rows. VGPR budget ~115 (acco 32 +
// qf 16 + sc 16 + ap 8 + accl 4 + addr) fits the 128-cap a 1024-thread block
// requires -> 4 waves/SIMD for latency hiding (was 2). Softmax: Q pre-scaled
// (no per-element mul) + native __bf16 casts (compiler cvt_pk) instead of
// manual-RNE f2bf. Loop structure / layouts identical to the proven version.
#if __has_builtin(__builtin_amdgcn_mfma_f32_16x16x16bf16_1k)
#define HAS_MFMA16 1
#endif

__global__ __launch_bounds__(1024, 4) void flash_k(const u16* __restrict__ Q,
                                                   const u16* __restrict__ Kc,
                                                   const u16* __restrict__ Vp,
                                                   u16* __restrict__ O) {
  __shared__ alignas(16) u16 sm[32768]; // 64KB
  const int tid = threadIdx.x;
  const int wave = tid >> 6, lane = tid & 63;
  const int quad = lane >> 4, l16 = lane & 15;
  const int qt = blockIdx.x, bh = blockIdx.y;
  const int b = bh >> 4, h = bh & 15;
  const u16* vbase_g = Vp + (size_t)bh * S_ * HD_;

  // stage Q (256 x 128, row-XOR swizzled 16B chunks) into ALL of sm
#pragma unroll
  for (int i = 0; i < 4; ++i) {
    int c = i * 1024 + tid, row = c >> 4, jl = c & 15;
    int gj = (jl & 8) | ((jl ^ row) & 7);
    GLD16(Q + ((size_t)bh * S_ + qt * 256 + row) * HD_ + gj * 8,
          sm + (size_t)(i * 1024 + wave * 64) * 8);
  }
  __syncthreads();

  bf16x8 qf[4]; // B-frag: n=l16 -> q row, k = dk*32+quad*8+j
  {
    int row = wave * 16 + l16;
#pragma unroll
    for (int dk = 0; dk < 4; ++dk) {
      int c = dk * 4 + quad, pj = (c & 8) | ((c ^ row) & 7);
      qf[dk] = *(const bf16x8*)&sm[row * 128 + pj * 8];
    }
  }
  __syncthreads(); // all waves done reading Q before K/V staging clobbers sm

  // stage K/V tile 0 into buf1 = sm[16384..32768); one 16B load per thread each
  {
    int c = tid, row = c >> 4, jl = c & 15;
    int gj = (jl & 8) | ((jl ^ row) & 7);
    GLD16(Kc + ((size_t)bh * S_ + row) * HD_ + gj * 8,
          sm + 16384 + (size_t)(wave * 64) * 8);
    GLD16(vbase_g + (size_t)tid * 8,
          sm + 24576 + (size_t)(wave * 64) * 8);
  }
  __syncthreads();

  f32x4 acco[8] = {};
  f32x4 accl = {};
#ifdef HAS_MFMA16
  const s16x4 ones = {(short)0x3F80, (short)0x3F80, (short)0x3F80, (short)0x3F80};
#else
  union { s16x8 s; bf16x8 b; } onesu;
  onesu.s = (s16x8){(short)0x3F80, (short)0x3F80, (short)0x3F80, (short)0x3F80,
                    (short)0x3F80, (short)0x3F80, (short)0x3F80, (short)0x3F80};
#endif

#pragma unroll 1
  for (int kt = 0; kt < 32; ++kt) {
    u16* cb = sm + ((kt & 1) ? 0 : 16384);
    u16* nb = sm + ((kt & 1) ? 16384 : 0);
    if (kt < 31) {
      int c = tid, row = c >> 4, jl = c & 15;
      int gj = (jl & 8) | ((jl ^ row) & 7);
      GLD16(Kc + ((size_t)bh * S_ + (kt + 1) * 64 + row) * HD_ + gj * 8,
            nb + (size_t)(wave * 64) * 8);
      GLD16(vbase_g + (size_t)(kt + 1) * 8192 + (size_t)tid * 8,
            nb + 8192 + (size_t)(wave * 64) * 8);
    }

    // S^T = K Q^T : A = K rows (m=kv), B = Q (n=q). Q pre-scaled by SCL.
    f32x4 sc[4] = {};
#pragma unroll
    for (int k4 = 0; k4 < 4; ++k4) {
      int row = k4 * 16 + l16;
#pragma unroll
      for (int dk = 0; dk < 4; ++dk) {
        int c = dk * 4 + quad, pj = (c & 8) | ((c ^ row) & 7);
        bf16x8 kf = *(const bf16x8*)&cb[row * 128 + pj * 8];
        sc[k4] = __builtin_amdgcn_mfma_f32_16x16x32_bf16(kf, qf[dk], sc[k4], 0, 0, 0);
      }
    }

    // P = exp2(S^T), packed to bf16 A-frags via native casts (k = kv = quad*4+j)
#ifdef HAS_MFMA16
    s16x4 ap[4];
#pragma unroll
    for (int k4 = 0; k4 < 4; ++k4) {
      f32x4 s = sc[k4];
      union { s16x4 s4; __bf16 bb[4]; } pu;
      pu.bb[0] = (__bf16)__builtin_amdgcn_exp2f(s[0]);
      pu.bb[1] = (__bf16)__builtin_amdgcn_exp2f(s[1]);
      pu.bb[2] = (__bf16)__builtin_amdgcn_exp2f(s[2]);
      pu.bb[3] = (__bf16)__builtin_amdgcn_exp2f(s[3]);
      ap[k4] = pu.s4;
    }
#else
    bf16x8 ap[4];
#pragma unroll
    for (int k4 = 0; k4 < 4; ++k4) {
      f32x4 s = sc[k4];
      union { s16x8 s8; bf16x8 b8; __bf16 bb[8]; } pu;
      pu.s8 = (s16x8){0, 0, 0, 0, 0, 0, 0, 0};
      pu.bb[0] = (__bf16)__builtin_amdgcn_exp2f(s[0]);
      pu.bb[1] = (__bf16)__builtin_amdgcn_exp2f(s[1]);
      pu.bb[2] = (__bf16)__builtin_amdgcn_exp2f(s[2]);
      pu.bb[3] = (__bf16)__builtin_amdgcn_exp2f(s[3]);
      ap[k4] = pu.b8;
    }
#endif

    // O += P V (P from regs; V b-frag = one b64 read), l via ones-MFMA
#pragma unroll
    for (int ck = 0; ck < 4; ++ck) {
      int vb = 8192 + (ck * 4 + quad) * 512 + l16 * 4;
#pragma unroll
      for (int df = 0; df < 8; ++df) {
        s16x4 bv = *(const s16x4*)&cb[vb + df * 64];
#ifdef HAS_MFMA16
        acco[df] = __builtin_amdgcn_mfma_f32_16x16x16bf16_1k(ap[ck], bv, acco[df], 0, 0, 0);
#else
        union { s16x8 s8; bf16x8 b8; } vbu;
        vbu.s8 = (s16x8){bv[0], bv[1], bv[2], bv[3], 0, 0, 0, 0};
        acco[df] = __builtin_amdgcn_mfma_f32_16x16x32_bf16(ap[ck], vbu.b8, acco[df], 0, 0, 0);
#endif
      }
#ifdef HAS_MFMA16
      accl = __builtin_amdgcn_mfma_f32_16x16x16bf16_1k(ones, ap[ck], accl, 0, 0, 0);
#else
      accl = __builtin_amdgcn_mfma_f32_16x16x32_bf16(onesu.b, ap[ck], accl, 0, 0, 0);
#endif
    }
    __syncthreads();
  }

  // epilogue: O rows q = quad*4+r, cols d = df*16+l16 ; l[q] lives at lane l16=q
  {
    float lv = accl[0];
    float linv[4];
#pragma unroll
    for (int r = 0; r < 4; ++r) linv[r] = 1.0f / __shfl(lv, quad * 4 + r);
    int rowb = qt * 256 + wave * 16 + quad * 4;
#pragma unroll
    for (int df = 0; df < 8; ++df) {
      int col = h * HD_ + df * 16 + l16;
#pragma unroll
      for (int r = 0; r < 4; ++r) {
        union { u16 u; __bf16 bb; } ou;
        ou.bb = (__bf16)(acco[df][r] * linv[r]);
        O[((size_t)(b * S_ + rowb + r)) * D_ + col] = ou.u;
      }
    }
  }
}

extern "C" void kernel_launch(void* const* d_in, const int* in_sizes, int n_in,
                              void* d_out, int out_size, void* d_ws, size_t ws_size,
                              hipStream_t stream) {
  const float* x  = (const float*)d_in[0];
  const float* wq = (const float*)d_in[1];
  const float* wk = (const float*)d_in[2];
  const float* wv = (const float*)d_in[3];
  const float* wo = (const float*)d_in[4];

  size_t off = 0;
  char* ws = (char*)d_ws;
  u16* xb    = (u16*)(ws + off); off += (size_t)M_ * D_ * 2;
  u16* wqkvb = (u16*)(ws + off); off += (size_t)3 * D_ * D_ * 2;
  u16* wob   = (u16*)(ws + off); off += (size_t)D_ * D_ * 2;
  u16* qkv   = (u16*)(ws + off); off += (size_t)M_ * N3_ * 2;
  u16* Qr    = (u16*)(ws + off); off += (size_t)M_ * D_ * 2;
  u16* Kr    = (u16*)(ws + off); off += (size_t)M_ * D_ * 2;
  u16* Vp    = (u16*)(ws + off); off += (size_t)M_ * D_ * 2;
  float2* tab = (float2*)(ws + off); off += (size_t)S_ * 64 * sizeof(float2);
  u16* Ob = qkv; // qkv dead after rope_k + vperm_k; reuse for attention output
  if (off > ws_size) return;

  cvt5_k<<<dim3(M_ * D_ / 4 / 256, 5), 256, 0, stream>>>(x, wq, wk, wv, wo, xb, wqkvb, wob);
  rope_tab_k<<<(S_ * 64) / 256, 256, 0, stream>>>(tab);
  gemm256_k<u16><<<(M_ / 256) * (N3_ / 256), 512, 0, stream>>>(xb, wqkvb, qkv, M_, N3_, D_);
  rope_k<<<(M_ * H_ * 64) / 256, 256, 0, stream>>>(qkv, tab, Qr, Kr);
  vperm_k<<<dim3(S_ * HD_ / 4 / 256, B_ * H_), 256, 0, stream>>>(qkv, Vp);
  flash_k<<<dim3(S_ / 256, B_ * H_), 1024, 0, stream>>>(Qr, Kr, Vp, Ob);
  gemm_bt_k<float><<<dim3(D_ / 128, M_ / 128), 256, 0, stream>>>(Ob, wob, (float*)d_out, M_, D_, D_);
}

// Round 8
// 392.007 us; speedup vs baseline: 1.0463x; 1.0463x over previous
//
#include <hip/hip_runtime.h>
#include <math.h>

typedef unsigned short u16;
typedef __bf16 bf16x8 __attribute__((ext_vector_type(8)));
typedef short s16x4 __attribute__((ext_vector_type(4)));
typedef short s16x8 __attribute__((ext_vector_type(8)));
typedef float f32x4 __attribute__((ext_vector_type(4)));

#define B_ 2
#define S_ 2048
#define D_ 2048
#define H_ 16
#define HD_ 128
#define M_ 4096
#define N3_ 6144

#define AS1(p) ((__attribute__((address_space(1))) void*)(void*)(p))
#define AS3(p) ((__attribute__((address_space(3))) void*)(p))
#define GLD16(g, l) __builtin_amdgcn_global_load_lds(AS1(g), AS3(l), 16, 0, 0)

__device__ __forceinline__ u16 f2bf(float f) {
  unsigned u = __float_as_uint(f);
  return (u16)((u + 0x7FFFu + ((u >> 16) & 1u)) >> 16);
}
__device__ __forceinline__ float bf2f(u16 v) {
  return __uint_as_float(((unsigned)v) << 16);
}

// ---------------- fp32 -> bf16 convert, all 5 tensors in one launch ----------------
__global__ void cvt5_k(const float* __restrict__ x, const float* __restrict__ wq,
                       const float* __restrict__ wk, const float* __restrict__ wv,
                       const float* __restrict__ wo, u16* __restrict__ xb,
                       u16* __restrict__ wqkvb, u16* __restrict__ wob) {
  int y = blockIdx.y;
  const float* s;
  u16* d;
  int n4;
  if (y == 0) {
    s = x; d = xb; n4 = M_ * D_ / 4;
  } else {
    s = (y == 1) ? wq : (y == 2) ? wk : (y == 3) ? wv : wo;
    d = (y == 4) ? wob : wqkvb + (size_t)(y - 1) * D_ * D_;
    n4 = D_ * D_ / 4;
  }
  int i = blockIdx.x * 256 + threadIdx.x;
  if (i >= n4) return;
  float4 v = ((const float4*)s)[i];
  ushort4 o;
  o.x = f2bf(v.x); o.y = f2bf(v.y); o.z = f2bf(v.z); o.w = f2bf(v.w);
  ((ushort4*)d)[i] = o;
}

// ---------------- RoPE cos/sin table (fp64 for accuracy) ----------------
__global__ void rope_tab_k(float2* __restrict__ tab) {
  int t = blockIdx.x * 256 + threadIdx.x;
  if (t >= S_ * 64) return;
  int s = t >> 6, i = t & 63;
  double inv = exp2(-(double)i * (13.287712379549449 / 64.0)); // 10000^(-i/64)
  double fr = (double)s * inv;
  double sv, cv;
  sincos(fr, &sv, &cv);
  tab[t] = make_float2((float)cv, (float)sv);
}

// ---------------- 256x256 8-phase GEMM (round-3 proven: 125.6us, 0 conflicts) ----
template <typename OT>
__global__ __launch_bounds__(512, 2) void gemm256_k(const u16* __restrict__ A,
                                                    const u16* __restrict__ B,
                                                    OT* __restrict__ C,
                                                    int M, int N, int K) {
  __shared__ alignas(16) u16 sm[65536]; // A0 A1 B0 B1, 16384 u16 each
  const int tid = threadIdx.x;
  const int wid = tid >> 6, lane = tid & 63;
  const int quad = lane >> 4, l16 = lane & 15;
  const int wr = wid >> 2, wc = wid & 3;

  const int nby = M >> 8, nbx = N >> 8, nwg = nbx * nby;
  int bid = blockIdx.x;
  int wg = (nwg % 8 == 0) ? (bid % 8) * (nwg >> 3) + (bid >> 3) : bid;
  const int m0 = (wg % nby) << 8, n0 = (wg / nby) << 8;

  const int rr = tid >> 3;
  const int sw8 = ((tid & 7) ^ (rr & 7)) * 8;
  const int gb0 = (rr & 31) + ((rr & 32) << 1);
  const u16* pA0_0 = A + (size_t)(m0 + rr) * K + sw8;
  const u16* pA0_1 = A + (size_t)(m0 + 128 + rr) * K + sw8;
  const u16* pA1_0 = A + (size_t)(m0 + 64 + rr) * K + sw8;
  const u16* pA1_1 = A + (size_t)(m0 + 192 + rr) * K + sw8;
  const u16* pB0_0 = B + (size_t)(n0 + gb0) * K + sw8;
  const u16* pB0_1 = B + (size_t)(n0 + 128 + gb0) * K + sw8;
  const u16* pB1_0 = B + (size_t)(n0 + 32 + gb0) * K + sw8;
  const u16* pB1_1 = B + (size_t)(n0 + 160 + gb0) * K + sw8;
  const int dst0 = wid * 64 * 8, dst1 = (512 + wid * 64) * 8;

  const int pj0 = (quad ^ (l16 & 7)) * 8;
  const int pj1 = ((4 + quad) ^ (l16 & 7)) * 8;

  f32x4 acc[8][4] = {};
  const int NT = K >> 6;

  GLD16(pA0_0, sm + dst0);
  GLD16(pA0_1, sm + dst1);
  GLD16(pB0_0, sm + 32768 + dst0);
  GLD16(pB0_1, sm + 32768 + dst1);
  GLD16(pB1_0, sm + 32768 + 8192 + dst0);
  GLD16(pB1_1, sm + 32768 + 8192 + dst1);
  GLD16(pA1_0, sm + 8192 + dst0);
  GLD16(pA1_1, sm + 8192 + dst1);
  asm volatile("s_waitcnt vmcnt(4)" ::: "memory");
  asm volatile("s_barrier" ::: "memory");

  int koff = 0;
#pragma unroll 1
  for (int t = 0; t < NT; ++t) {
    const int aB = (t & 1) * 16384, bB = 32768 + (t & 1) * 16384;
    const int aN = ((t + 1) & 1) * 16384, bN = 32768 + ((t + 1) & 1) * 16384;
    const bool pre = (t + 1 < NT);
    const int kn = koff + 64;
    bf16x8 a_[4][2], b_[4][2];

    // ---- P0
#pragma unroll
    for (int m = 0; m < 4; ++m) {
      int rb = aB + (wr * 64 + m * 16 + l16) * 64;
      a_[m][0] = *(const bf16x8*)&sm[rb + pj0];
      a_[m][1] = *(const bf16x8*)&sm[rb + pj1];
    }
#pragma unroll
    for (int n = 0; n < 2; ++n) {
      int rb = bB + (wc * 32 + n * 16 + l16) * 64;
      b_[n][0] = *(const bf16x8*)&sm[rb + pj0];
      b_[n][1] = *(const bf16x8*)&sm[rb + pj1];
    }
    if (pre) { GLD16(pA0_0 + kn, sm + aN + dst0); GLD16(pA0_1 + kn, sm + aN + dst1); }
    asm volatile("s_barrier" ::: "memory");
    __builtin_amdgcn_s_setprio(1);
#pragma unroll
    for (int m = 0; m < 4; ++m)
#pragma unroll
      for (int n = 0; n < 2; ++n) {
        acc[m][n] = __builtin_amdgcn_mfma_f32_16x16x32_bf16(a_[m][0], b_[n][0], acc[m][n], 0, 0, 0);
        acc[m][n] = __builtin_amdgcn_mfma_f32_16x16x32_bf16(a_[m][1], b_[n][1], acc[m][n], 0, 0, 0);
      }
    __builtin_amdgcn_s_setprio(0);
    if (pre) asm volatile("s_waitcnt vmcnt(4)" ::: "memory");
    else     asm volatile("s_waitcnt vmcnt(0)" ::: "memory");
    asm volatile("s_barrier" ::: "memory");

    // ---- P1
#pragma unroll
    for (int n = 0; n < 2; ++n) {
      int rb = bB + (128 + wc * 32 + n * 16 + l16) * 64;
      b_[2 + n][0] = *(const bf16x8*)&sm[rb + pj0];
      b_[2 + n][1] = *(const bf16x8*)&sm[rb + pj1];
    }
    if (pre) { GLD16(pB0_0 + kn, sm + bN + dst0); GLD16(pB0_1 + kn, sm + bN + dst1); }
    asm volatile("s_barrier" ::: "memory");
    __builtin_amdgcn_s_setprio(1);
#pragma unroll
    for (int m = 0; m < 4; ++m)
#pragma unroll
      for (int n = 0; n < 2; ++n) {
        acc[m][2 + n] = __builtin_amdgcn_mfma_f32_16x16x32_bf16(a_[m][0], b_[2 + n][0], acc[m][2 + n], 0, 0, 0);
        acc[m][2 + n] = __builtin_amdgcn_mfma_f32_16x16x32_bf16(a_[m][1], b_[2 + n][1], acc[m][2 + n], 0, 0, 0);
      }
    __builtin_amdgcn_s_setprio(0);
    if (pre) asm volatile("s_waitcnt vmcnt(4)" ::: "memory");
    else     asm volatile("s_waitcnt vmcnt(0)" ::: "memory");
    asm volatile("s_barrier" ::: "memory");

    // ---- P2
#pragma unroll
    for (int m = 0; m < 4; ++m) {
      int rb = aB + (128 + wr * 64 + m * 16 + l16) * 64;
      a_[m][0] = *(const bf16x8*)&sm[rb + pj0];
      a_[m][1] = *(const bf16x8*)&sm[rb + pj1];
    }
    if (pre) { GLD16(pB1_0 + kn, sm + bN + 8192 + dst0); GLD16(pB1_1 + kn, sm + bN + 8192 + dst1); }
    asm volatile("s_barrier" ::: "memory");
    __builtin_amdgcn_s_setprio(1);
#pragma unroll
    for (int m = 0; m < 4; ++m)
#pragma unroll
      for (int n = 0; n < 2; ++n) {
        acc[4 + m][n] = __builtin_amdgcn_mfma_f32_16x16x32_bf16(a_[m][0], b_[n][0], acc[4 + m][n], 0, 0, 0);
        acc[4 + m][n] = __builtin_amdgcn_mfma_f32_16x16x32_bf16(a_[m][1], b_[n][1], acc[4 + m][n], 0, 0, 0);
      }
    __builtin_amdgcn_s_setprio(0);
    asm volatile("s_barrier" ::: "memory");

    // ---- P3
    if (pre) { GLD16(pA1_0 + kn, sm + aN + 8192 + dst0); GLD16(pA1_1 + kn, sm + aN + 8192 + dst1); }
    asm volatile("s_barrier" ::: "memory");
    __builtin_amdgcn_s_setprio(1);
#pragma unroll
    for (int m = 0; m < 4; ++m)
#pragma unroll
      for (int n = 0; n < 2; ++n) {
        acc[4 + m][2 + n] = __builtin_amdgcn_mfma_f32_16x16x32_bf16(a_[m][0], b_[2 + n][0], acc[4 + m][2 + n], 0, 0, 0);
        acc[4 + m][2 + n] = __builtin_amdgcn_mfma_f32_16x16x32_bf16(a_[m][1], b_[2 + n][1], acc[4 + m][2 + n], 0, 0, 0);
      }
    __builtin_amdgcn_s_setprio(0);
    asm volatile("s_waitcnt vmcnt(4)" ::: "memory");
    asm volatile("s_barrier" ::: "memory");
    koff = kn;
  }

#pragma unroll
  for (int m = 0; m < 8; ++m) {
#pragma unroll
    for (int n = 0; n < 4; ++n) {
      int col = n0 + wc * 64 + n * 16 + l16;
#pragma unroll
      for (int r = 0; r < 4; ++r) {
        int row = m0 + wr * 128 + m * 16 + quad * 4 + r;
        if constexpr (sizeof(OT) == 4)
          C[(size_t)row * N + col] = acc[m][n][r];
        else
          C[(size_t)row * N + col] = f2bf(acc[m][n][r]);
      }
    }
  }
}

// ---------------- 128x256 2-phase GEMM (out-proj: 32x8 = 256 blocks = 1 exact round) --
// Same verified schedule skeleton as gemm256_k: per tile 2 phases, each
// {ds_read frags; stage chunk(s) of t+1 into other-parity buffer; barrier;
// setprio(1); 16 MFMA; setprio(0); counted vmcnt; barrier}. Chunks (16KB):
// A (rows 0-127 natural), B0 (n-frags 0-1: rows {0-31,64-95,128-159,192-223}
// via gb0), B1 (+32). Stage {A,B0}^{t+1}@P0, B1^{t+1}@P1. FIFO ledger:
// prologue [A,B0,B1] -> vmcnt(2); P0-end vmcnt(4) retires B1^t; P1-end
// vmcnt(2) retires {A,B0}^{t+1}; invariant [B1(2)]; windows all >=2 phases.
// LDS 96KB: A[2][128][64]@0, B[2][256][64]@16384(u16). Chunk-XOR swizzle
// both-sides, identical formulas to gemm256_k (measured 0 conflicts there).
template <typename OT>
__global__ __launch_bounds__(512, 2) void gemmw_k(const u16* __restrict__ A,
                                                  const u16* __restrict__ B,
                                                  OT* __restrict__ C,
                                                  int M, int N, int K) {
  __shared__ alignas(16) u16 sm[49152]; // A0@0 A1@8192 Bbuf0@16384 Bbuf1@32768
  const int tid = threadIdx.x;
  const int wid = tid >> 6, lane = tid & 63;
  const int quad = lane >> 4, l16 = lane & 15;
  const int wr = wid >> 2, wc = wid & 3; // wave owns 64x64: rows wr*64, cols wc*64

  const int nbm = M >> 7, nbn = N >> 8, nwg = nbm * nbn;
  int bid = blockIdx.x;
  int wg = (nwg % 8 == 0) ? (bid % 8) * (nwg >> 3) + (bid >> 3) : bid;
  const int m0 = (wg % nbm) << 7, n0 = (wg / nbm) << 8;

  const int rr = tid >> 3;
  const int sw8 = ((tid & 7) ^ (rr & 7)) * 8;
  const int gb0 = (rr & 31) + ((rr & 32) << 1);
  const u16* pA_0 = A + (size_t)(m0 + rr) * K + sw8;
  const u16* pA_1 = A + (size_t)(m0 + 64 + rr) * K + sw8;
  const u16* pB0_0 = B + (size_t)(n0 + gb0) * K + sw8;
  const u16* pB0_1 = B + (size_t)(n0 + 128 + gb0) * K + sw8;
  const u16* pB1_0 = B + (size_t)(n0 + 32 + gb0) * K + sw8;
  const u16* pB1_1 = B + (size_t)(n0 + 160 + gb0) * K + sw8;
  const int dst0 = wid * 512, dst1 = 4096 + wid * 512; // u16 offsets (8KB per op)

  const int pj0 = (quad ^ (l16 & 7)) * 8;
  const int pj1 = ((4 + quad) ^ (l16 & 7)) * 8;

  f32x4 acc[4][4] = {};
  const int NT = K >> 6;

  // prologue: stage tile 0 chunks A, B0, B1; retire A, B0
  GLD16(pA_0, sm + dst0);          GLD16(pA_1, sm + dst1);
  GLD16(pB0_0, sm + 16384 + dst0); GLD16(pB0_1, sm + 16384 + dst1);
  GLD16(pB1_0, sm + 24576 + dst0); GLD16(pB1_1, sm + 24576 + dst1);
  asm volatile("s_waitcnt vmcnt(2)" ::: "memory");
  asm volatile("s_barrier" ::: "memory");

  int koff = 0;
#pragma unroll 1
  for (int t = 0; t < NT; ++t) {
    const int aB = (t & 1) * 8192, bB = 16384 + (t & 1) * 16384;
    const int aN = ((t + 1) & 1) * 8192, bN = 16384 + ((t + 1) & 1) * 16384;
    const bool pre = (t + 1 < NT);
    const int kn = koff + 64;
    bf16x8 a_[4][2], b_[4][2];

    // ---- P0: read a(m0-3) + b(n0-1); stage A^{t+1}, B0^{t+1}; MFMA m0-3 x n0-1
#pragma unroll
    for (int m = 0; m < 4; ++m) {
      int rb = aB + (wr * 64 + m * 16 + l16) * 64;
      a_[m][0] = *(const bf16x8*)&sm[rb + pj0];
      a_[m][1] = *(const bf16x8*)&sm[rb + pj1];
    }
#pragma unroll
    for (int n = 0; n < 2; ++n) {
      int rb = bB + (wc * 32 + n * 16 + l16) * 64;
      b_[n][0] = *(const bf16x8*)&sm[rb + pj0];
      b_[n][1] = *(const bf16x8*)&sm[rb + pj1];
    }
    if (pre) {
      GLD16(pA_0 + kn, sm + aN + dst0);  GLD16(pA_1 + kn, sm + aN + dst1);
      GLD16(pB0_0 + kn, sm + bN + dst0); GLD16(pB0_1 + kn, sm + bN + dst1);
    }
    asm volatile("s_barrier" ::: "memory");
    __builtin_amdgcn_s_setprio(1);
#pragma unroll
    for (int m = 0; m < 4; ++m)
#pragma unroll
      for (int n = 0; n < 2; ++n) {
        acc[m][n] = __builtin_amdgcn_mfma_f32_16x16x32_bf16(a_[m][0], b_[n][0], acc[m][n], 0, 0, 0);
        acc[m][n] = __builtin_amdgcn_mfma_f32_16x16x32_bf16(a_[m][1], b_[n][1], acc[m][n], 0, 0, 0);
      }
    __builtin_amdgcn_s_setprio(0);
    if (pre) asm volatile("s_waitcnt vmcnt(4)" ::: "memory"); // retires B1^t
    else     asm volatile("s_waitcnt vmcnt(0)" ::: "memory");
    asm volatile("s_barrier" ::: "memory");

    // ---- P1: read b(n2-3) from B1 chunk; stage B1^{t+1}; MFMA m0-3 x n2-3
#pragma unroll
    for (int n = 0; n < 2; ++n) {
      int rb = bB + 8192 + (wc * 32 + n * 16 + l16) * 64;
      b_[2 + n][0] = *(const bf16x8*)&sm[rb + pj0];
      b_[2 + n][1] = *(const bf16x8*)&sm[rb + pj1];
    }
    if (pre) { GLD16(pB1_0 + kn, sm + bN + 8192 + dst0); GLD16(pB1_1 + kn, sm + bN + 8192 + dst1); }
    asm volatile("s_barrier" ::: "memory");
    __builtin_amdgcn_s_setprio(1);
#pragma unroll
    for (int m = 0; m < 4; ++m)
#pragma unroll
      for (int n = 0; n < 2; ++n) {
        acc[m][2 + n] = __builtin_amdgcn_mfma_f32_16x16x32_bf16(a_[m][0], b_[2 + n][0], acc[m][2 + n], 0, 0, 0);
        acc[m][2 + n] = __builtin_amdgcn_mfma_f32_16x16x32_bf16(a_[m][1], b_[2 + n][1], acc[m][2 + n], 0, 0, 0);
      }
    __builtin_amdgcn_s_setprio(0);
    if (pre) asm volatile("s_waitcnt vmcnt(2)" ::: "memory"); // retires A^{t+1}, B0^{t+1}
    else     asm volatile("s_waitcnt vmcnt(0)" ::: "memory");
    asm volatile("s_barrier" ::: "memory");
    koff = kn;
  }

  // epilogue: rows m0 + wr*64 + m*16 + quad*4 + r, cols n0 + wc*64 + n*16 + l16
#pragma unroll
  for (int m = 0; m < 4; ++m) {
#pragma unroll
    for (int n = 0; n < 4; ++n) {
      int col = n0 + wc * 64 + n * 16 + l16;
#pragma unroll
      for (int r = 0; r < 4; ++r) {
        int row = m0 + wr * 64 + m * 16 + quad * 4 + r;
        if constexpr (sizeof(OT) == 4)
          C[(size_t)row * N + col] = acc[m][n][r];
        else
          C[(size_t)row * N + col] = f2bf(acc[m][n][r]);
      }
    }
  }
}

// ---------------- RoPE apply + relayout q,k -> [b*H+h][s][d] ----------------
// Q additionally pre-scaled by 1/sqrt(128)*log2(e) so flash applies exp2 directly.
__global__ void rope_k(const u16* __restrict__ qkv, const float2* __restrict__ tab,
                       u16* __restrict__ Qr, u16* __restrict__ Kr) {
  const float SCLQ = 0.08838834764831845f * 1.4426950408889634f;
  int t = blockIdx.x * 256 + threadIdx.x; // M_*H_*64
  int m = t >> 10;
  int h = (t >> 6) & 15;
  int i = t & 63;
  int s = m & (S_ - 1);
  int b = m >> 11;
  float2 cs = tab[(s << 6) | i];
  const u16* qp = qkv + (size_t)m * N3_ + h * HD_ + 2 * i;
  ushort2 qv = *(const ushort2*)qp;
  ushort2 kv = *(const ushort2*)(qp + D_);
  float qr = bf2f(qv.x), qi = bf2f(qv.y);
  float kr = bf2f(kv.x), ki = bf2f(kv.y);
  ushort2 qo, ko;
  qo.x = f2bf((qr * cs.x - qi * cs.y) * SCLQ);
  qo.y = f2bf((qr * cs.y + qi * cs.x) * SCLQ);
  ko.x = f2bf(kr * cs.x - ki * cs.y);
  ko.y = f2bf(kr * cs.y + ki * cs.x);
  size_t o = ((size_t)(b * H_ + h) * S_ + s) * HD_ + 2 * i;
  *(ushort2*)(Qr + o) = qo;
  *(ushort2*)(Kr + o) = ko;
}

// ---------------- V permute: qkv v-part -> Vp[bh][s/4][d][4] ----------------
__global__ __launch_bounds__(256) void vperm_k(const u16* __restrict__ qkv,
                                               u16* __restrict__ Vp) {
  int bh = blockIdx.y;
  int b = bh >> 4, h = bh & 15;
  int t = blockIdx.x * 256 + threadIdx.x; // 0 .. S_*HD_/4-1 ; t = g*128 + d
  int d = t & 127, g = t >> 7;
  const u16* src = qkv + ((size_t)(b * S_ + 4 * g)) * N3_ + 2 * D_ + h * HD_ + d;
  ushort4 o;
  o.x = src[0];
  o.y = src[N3_];
  o.z = src[2 * N3_];
  o.w = src[3 * N3_];
  *(ushort4*)(Vp + (size_t)bh * S_ * HD_ + (size_t)t * 4) = o;
}

// ---------------- Flash attention, q-tile 256, 16 waves, 4 waves/SIMD ----------------
#if __has_builtin(__builtin_amdgcn_mfma_f32_16x16x16bf16_1k)
#define HAS_MFMA16 1
#endif

__global__ __launch_bounds__(1024, 4) void flash_k(const u16* __restrict__ Q,
                                                   const u16* __restrict__ Kc,
                                                   const u16* __restrict__ Vp,
                                                   u16* __restrict__ O) {
  __shared__ alignas(16) u16 sm[32768]; // 64KB
  const int tid = threadIdx.x;
  const int wave = tid >> 6, lane = tid & 63;
  const int quad = lane >> 4, l16 = lane & 15;
  const int qt = blockIdx.x, bh = blockIdx.y;
  const int b = bh >> 4, h = bh & 15;
  const u16* vbase_g = Vp + (size_t)bh * S_ * HD_;

  // stage Q (256 x 128, row-XOR swizzled 16B chunks) into ALL of sm
#pragma unroll
  for (int i = 0; i < 4; ++i) {
    int c = i * 1024 + tid, row = c >> 4, jl = c & 15;
    int gj = (jl & 8) | ((jl ^ row) & 7);
    GLD16(Q + ((size_t)bh * S_ + qt * 256 + row) * HD_ + gj * 8,
          sm + (size_t)(i * 1024 + wave * 64) * 8);
  }
  __syncthreads();

  bf16x8 qf[4]; // B-frag: n=l16 -> q row, k = dk*32+quad*8+j
  {
    int row = wave * 16 + l16;
#pragma unroll
    for (int dk = 0; dk < 4; ++dk) {
      int c = dk * 4 + quad, pj = (c & 8) | ((c ^ row) & 7);
      qf[dk] = *(const bf16x8*)&sm[row * 128 + pj * 8];
    }
  }
  __syncthreads(); // all waves done reading Q before K/V staging clobbers sm

  // stage K/V tile 0 into buf1 = sm[16384..32768); one 16B load per thread each
  {
    int c = tid, row = c >> 4, jl = c & 15;
    int gj = (jl & 8) | ((jl ^ row) & 7);
    GLD16(Kc + ((size_t)bh * S_ + row) * HD_ + gj * 8,
          sm + 16384 + (size_t)(wave * 64) * 8);
    GLD16(vbase_g + (size_t)tid * 8,
          sm + 24576 + (size_t)(wave * 64) * 8);
  }
  __syncthreads();

  f32x4 acco[8] = {};
  f32x4 accl = {};
#ifdef HAS_MFMA16
  const s16x4 ones = {(short)0x3F80, (short)0x3F80, (short)0x3F80, (short)0x3F80};
#else
  union { s16x8 s; bf16x8 b; } onesu;
  onesu.s = (s16x8){(short)0x3F80, (short)0x3F80, (short)0x3F80, (short)0x3F80,
                    (short)0x3F80, (short)0x3F80, (short)0x3F80, (short)0x3F80};
#endif

#pragma unroll 1
  for (int kt = 0; kt < 32; ++kt) {
    u16* cb = sm + ((kt & 1) ? 0 : 16384);
    u16* nb = sm + ((kt & 1) ? 16384 : 0);
    if (kt < 31) {
      int c = tid, row = c >> 4, jl = c & 15;
      int gj = (jl & 8) | ((jl ^ row) & 7);
      GLD16(Kc + ((size_t)bh * S_ + (kt + 1) * 64 + row) * HD_ + gj * 8,
            nb + (size_t)(wave * 64) * 8);
      GLD16(vbase_g + (size_t)(kt + 1) * 8192 + (size_t)tid * 8,
            nb + 8192 + (size_t)(wave * 64) * 8);
    }

    // S^T = K Q^T : A = K rows (m=kv), B = Q (n=q). Q pre-scaled by SCL.
    f32x4 sc[4] = {};
#pragma unroll
    for (int k4 = 0; k4 < 4; ++k4) {
      int row = k4 * 16 + l16;
#pragma unroll
      for (int dk = 0; dk < 4; ++dk) {
        int c = dk * 4 + quad, pj = (c & 8) | ((c ^ row) & 7);
        bf16x8 kf = *(const bf16x8*)&cb[row * 128 + pj * 8];
        sc[k4] = __builtin_amdgcn_mfma_f32_16x16x32_bf16(kf, qf[dk], sc[k4], 0, 0, 0);
      }
    }

    // P = exp2(S^T), packed to bf16 A-frags via native casts (k = kv = quad*4+j)
#ifdef HAS_MFMA16
    s16x4 ap[4];
#pragma unroll
    for (int k4 = 0; k4 < 4; ++k4) {
      f32x4 s = sc[k4];
      union { s16x4 s4; __bf16 bb[4]; } pu;
      pu.bb[0] = (__bf16)__builtin_amdgcn_exp2f(s[0]);
      pu.bb[1] = (__bf16)__builtin_amdgcn_exp2f(s[1]);
      pu.bb[2] = (__bf16)__builtin_amdgcn_exp2f(s[2]);
      pu.bb[3] = (__bf16)__builtin_amdgcn_exp2f(s[3]);
      ap[k4] = pu.s4;
    }
#else
    bf16x8 ap[4];
#pragma unroll
    for (int k4 = 0; k4 < 4; ++k4) {
      f32x4 s = sc[k4];
      union { s16x8 s8; bf16x8 b8; __bf16 bb[8]; } pu;
      pu.s8 = (s16x8){0, 0, 0, 0, 0, 0, 0, 0};
      pu.bb[0] = (__bf16)__builtin_amdgcn_exp2f(s[0]);
      pu.bb[1] = (__bf16)__builtin_amdgcn_exp2f(s[1]);
      pu.bb[2] = (__bf16)__builtin_amdgcn_exp2f(s[2]);
      pu.bb[3] = (__bf16)__builtin_amdgcn_exp2f(s[3]);
      ap[k4] = pu.b8;
    }
#endif

    // O += P V (P from regs; V b-frag = one b64 read), l via ones-MFMA
#pragma unroll
    for (int ck = 0; ck < 4; ++ck) {
      int vb = 8192 + (ck * 4 + quad) * 512 + l16 * 4;
#pragma unroll
      for (int df = 0; df < 8; ++df) {
        s16x4 bv = *(const s16x4*)&cb[vb + df * 64];
#ifdef HAS_MFMA16
        acco[df] = __builtin_amdgcn_mfma_f32_16x16x16bf16_1k(ap[ck], bv, acco[df], 0, 0, 0);
#else
        union { s16x8 s8; bf16x8 b8; } vbu;
        vbu.s8 = (s16x8){bv[0], bv[1], bv[2], bv[3], 0, 0, 0, 0};
        acco[df] = __builtin_amdgcn_mfma_f32_16x16x32_bf16(ap[ck], vbu.b8, acco[df], 0, 0, 0);
#endif
      }
#ifdef HAS_MFMA16
      accl = __builtin_amdgcn_mfma_f32_16x16x16bf16_1k(ones, ap[ck], accl, 0, 0, 0);
#else
      accl = __builtin_amdgcn_mfma_f32_16x16x32_bf16(onesu.b, ap[ck], accl, 0, 0, 0);
#endif
    }
    __syncthreads();
  }

  // epilogue: O rows q = quad*4+r, cols d = df*16+l16 ; l[q] lives at lane l16=q
  {
    float lv = accl[0];
    float linv[4];
#pragma unroll
    for (int r = 0; r < 4; ++r) linv[r] = 1.0f / __shfl(lv, quad * 4 + r);
    int rowb = qt * 256 + wave * 16 + quad * 4;
#pragma unroll
    for (int df = 0; df < 8; ++df) {
      int col = h * HD_ + df * 16 + l16;
#pragma unroll
      for (int r = 0; r < 4; ++r) {
        union { u16 u; __bf16 bb; } ou;
        ou.bb = (__bf16)(acco[df][r] * linv[r]);
        O[((size_t)(b * S_ + rowb + r)) * D_ + col] = ou.u;
      }
    }
  }
}

extern "C" void kernel_launch(void* const* d_in, const int* in_sizes, int n_in,
                              void* d_out, int out_size, void* d_ws, size_t ws_size,
                              hipStream_t stream) {
  const float* x  = (const float*)d_in[0];
  const float* wq = (const float*)d_in[1];
  const float* wk = (const float*)d_in[2];
  const float* wv = (const float*)d_in[3];
  const float* wo = (const float*)d_in[4];

  size_t off = 0;
  char* ws = (char*)d_ws;
  u16* xb    = (u16*)(ws + off); off += (size_t)M_ * D_ * 2;
  u16* wqkvb = (u16*)(ws + off); off += (size_t)3 * D_ * D_ * 2;
  u16* wob   = (u16*)(ws + off); off += (size_t)D_ * D_ * 2;
  u16* qkv   = (u16*)(ws + off); off += (size_t)M_ * N3_ * 2;
  u16* Qr    = (u16*)(ws + off); off += (size_t)M_ * D_ * 2;
  u16* Kr    = (u16*)(ws + off); off += (size_t)M_ * D_ * 2;
  u16* Vp    = (u16*)(ws + off); off += (size_t)M_ * D_ * 2;
  float2* tab = (float2*)(ws + off); off += (size_t)S_ * 64 * sizeof(float2);
  u16* Ob = qkv; // qkv dead after rope_k + vperm_k; reuse for attention output
  if (off > ws_size) return;

  cvt5_k<<<dim3(M_ * D_ / 4 / 256, 5), 256, 0, stream>>>(x, wq, wk, wv, wo, xb, wqkvb, wob);
  rope_tab_k<<<(S_ * 64) / 256, 256, 0, stream>>>(tab);
  gemm256_k<u16><<<(M_ / 256) * (N3_ / 256), 512, 0, stream>>>(xb, wqkvb, qkv, M_, N3_, D_);
  rope_k<<<(M_ * H_ * 64) / 256, 256, 0, stream>>>(qkv, tab, Qr, Kr);
  vperm_k<<<dim3(S_ * HD_ / 4 / 256, B_ * H_), 256, 0, stream>>>(qkv, Vp);
  flash_k<<<dim3(S_ / 256, B_ * H_), 1024, 0, stream>>>(Qr, Kr, Vp, Ob);
  gemmw_k<float><<<(M_ / 128) * (D_ / 256), 512, 0, stream>>>(Ob, wob, (float*)d_out, M_, D_, D_);
}